// Round 10
// baseline (211.862 us; speedup 1.0000x reference)
//
#include <hip/hip_runtime.h>
#include <hip/hip_bf16.h>

#define BB 8
#define NN 16384
#define D1 256
#define D2 64
#define DT 320
#define EPSF 1e-12f
#define NCG 16          // K chunks
#define KCH 1024        // rows per chunk (16 tiles of 64)
#define QSZ (160*320)   // partial slice elems

typedef __attribute__((ext_vector_type(8))) short bf16x8;
typedef __attribute__((ext_vector_type(8))) unsigned short u16x8;
typedef __attribute__((ext_vector_type(4))) float f32x4;
typedef __attribute__((ext_vector_type(4))) unsigned int u32x4;

__device__ __forceinline__ unsigned int packbf2(float a, float b) {
    unsigned short lo = __builtin_bit_cast(unsigned short, __float2bfloat16(a));
    unsigned short hi = __builtin_bit_cast(unsigned short, __float2bfloat16(b));
    return (unsigned int)lo | ((unsigned int)hi << 16);
}
__device__ __forceinline__ unsigned short f2bfu(float f) {
    return __builtin_bit_cast(unsigned short, __float2bfloat16(f));
}
__device__ __forceinline__ float bf2f(unsigned short u) {
    unsigned int x = (unsigned int)u << 16;
    return __builtin_bit_cast(float, x);
}

// 8-unit swizzle over [c][64-row] bf16 tile: element (c, n8*8+k) lives at unit
// u = (n8 ^ sig(c)) & 7 of row c. [R3/R6-verified clean for frag reads]
__device__ __forceinline__ int sig(int c) { return (c ^ (c >> 2)) & 7; }

// validated in R7: per-lane global src, wave-uniform LDS base + lane*16
__device__ __forceinline__ void gload16(const unsigned short* g, unsigned short* l) {
    __builtin_amdgcn_global_load_lds(
        (const __attribute__((address_space(1))) unsigned int*)(g),
        (__attribute__((address_space(3))) unsigned int*)(l), 16, 0, 0);
}

// ---------------- kernel 1: s[b,c] = sum_n Y[b,n,c] ----------------
__global__ void colsum_kernel(const float* __restrict__ Y, float* __restrict__ s) {
    const int b = blockIdx.y;
    const int chunk = blockIdx.x;
    const int t = threadIdx.x;
    const int c = t & 63;
    const int r = t >> 6;
    const float* Yb = Y + (size_t)b * NN * D2;
    float acc = 0.f;
    const int nbase = chunk * 512;
    for (int k = 0; k < 128; ++k) {
        int n = nbase + k * 4 + r;
        acc += Yb[(size_t)n * D2 + c];
    }
    __shared__ float red[256];
    red[t] = acc;
    __syncthreads();
    if (r == 0) {
        float v = red[c] + red[64 + c] + red[128 + c] + red[192 + c];
        atomicAdd(&s[b * D2 + c], v);
    }
}

// ---------------- kernel 2: rsd[b,n] = (Y[b,n,:].s[b,:] + eps)^(-1/4) ----------------
__global__ void rsd_kernel(const float* __restrict__ Y, const float* __restrict__ s,
                           float* __restrict__ rsd) {
    const int blk = blockIdx.x;
    const int b = blk >> 8;
    const int nb = (blk & 255) * 64;
    const int t = threadIdx.x;
    const int q = t & 3;
    const int nl = t >> 2;
    __shared__ float ss[D2];
    if (t < D2) ss[t] = s[b * D2 + t];
    __syncthreads();
    const int n = nb + nl;
    const float* yrow = Y + (size_t)b * NN * D2 + (size_t)n * D2 + q * 16;
    float dot = 0.f;
#pragma unroll
    for (int i = 0; i < 4; ++i) {
        float4 f = *reinterpret_cast<const float4*>(yrow + i * 4);
        const float* sp = ss + q * 16 + i * 4;
        dot += f.x * sp[0] + f.y * sp[1] + f.z * sp[2] + f.w * sp[3];
    }
    dot += __shfl_xor(dot, 1);
    dot += __shfl_xor(dot, 2);
    if (q == 0) {
        rsd[(size_t)b * NN + n] = rsqrtf(sqrtf(dot + EPSF));
    }
}

// ---------------- kernel 3: Xs = scaled bf16 tiles in gram-ready swizzled layout ----
// Xs tile (b, nt): 40 KB = [c=0..319][u=0..7][k=0..7], value X[n][c]*rsd[n],
// n = nt*64 + 8*(u^sig(c)) + k.  grid (256 nt, 5 cseg, 8 b), 256 thr.
__global__ void xt2_kernel(const float* __restrict__ V, const float* __restrict__ Y,
                           const float* __restrict__ rsd, unsigned short* __restrict__ Xs) {
    const int nt = blockIdx.x;
    const int cs = blockIdx.y;
    const int b = blockIdx.z;
    const int t = threadIdx.x;
    const int n0 = nt * 64;
    const int r = t >> 2;           // local row 0..63
    const int cq = t & 3;           // 16-col group
    const bool isY = (cs == 4);
    const int c0g = isY ? D1 : cs * 64;      // global col base of this 64-col slab

    const int n = n0 + r;
    const float sc = rsd[(size_t)b * NN + n];
    const float* srow = isY
        ? (Y + ((size_t)b * NN + n) * D2 + cq * 16)
        : (V + ((size_t)b * NN + n) * D1 + cs * 64 + cq * 16);

    __shared__ __attribute__((aligned(16))) unsigned short tile[64 * 64];  // 8 KB

    const int k = r & 7;
    const int n8 = r >> 3;
#pragma unroll
    for (int ii = 0; ii < 4; ++ii) {
        float4 f = *reinterpret_cast<const float4*>(srow + ii * 4);
        const float* fp = &f.x;
#pragma unroll
        for (int e = 0; e < 4; ++e) {
            const int cl = cq * 16 + ii * 4 + e;          // local col 0..63
            const int u = (n8 ^ sig(c0g + cl)) & 7;
            tile[cl * 64 + u * 8 + k] = f2bfu(fp[e] * sc);
        }
    }
    __syncthreads();

    // dump 8 KB slab -> Xs tile rows [c0g, c0g+64)
    unsigned short* out = Xs + ((size_t)(b * 256 + nt) * DT + c0g) * 64;
#pragma unroll
    for (int q = 0; q < 2; ++q) {
        const int off = (q * 256 + t) * 8;
        *reinterpret_cast<u32x4*>(out + off) =
            *reinterpret_cast<const u32x4*>(&tile[off]);
    }
}

// ---------------- kernel 4: band Gram from Xs via global_load_lds -----------------
// grid (16 cg, 2 band, 8 b) = 256 blocks; 512 thr (8 waves 2x4 of 80x80).
// Staging = 5 async DMA per wave per tile, double-buffered. No staging VALU/regs.
__global__ void gram4_kernel(const unsigned short* __restrict__ Xs,
                             unsigned short* __restrict__ Gpart) {
    const int cg = blockIdx.x;
    const int band = blockIdx.y;
    const int b = blockIdx.z;
    const int t = threadIdx.x;
    const int lane = t & 63;
    const int w = t >> 6;
    const int wrow = w >> 2;
    const int wcol = w & 3;
    const int l15 = lane & 15;
    const int l4 = lane >> 4;

    __shared__ __attribute__((aligned(16))) unsigned short xb[2][DT * 64];  // 80 KB

    f32x4 acc[5][5];
#pragma unroll
    for (int i = 0; i < 5; ++i)
#pragma unroll
        for (int j = 0; j < 5; ++j)
            acc[i][j] = (f32x4){0.f, 0.f, 0.f, 0.f};

    const int nt0 = cg * (KCH / 64);
    const size_t Xb = (size_t)b * 256 * DT * 64;

    // stage tile nt into buf: per wave 5 x 1KB DMA, linear copy (swizzle pre-baked)
#define STAGE4(buf, nt)                                                          \
    {                                                                            \
        const unsigned short* tb = Xs + Xb + (size_t)(nt) * (DT * 64);           \
        _Pragma("unroll")                                                        \
        for (int rql = 0; rql < 5; ++rql) {                                      \
            const int eo = (w * 5 + rql) * 512;                                  \
            gload16(tb + eo + lane * 8, &xb[buf][eo]);                           \
        }                                                                        \
    }

    STAGE4(0, nt0);
    __syncthreads();                 // compiler drains vmcnt before barrier

    int cur = 0;
    for (int tt = 0; tt < KCH / 64; ++tt) {
        if (tt < KCH / 64 - 1) STAGE4(cur ^ 1, nt0 + tt + 1);   // async during MFMA

        const unsigned short* x = xb[cur];
#pragma unroll
        for (int ks = 0; ks < 2; ++ks) {
            const int n8r = 2 * l4 + ks;     // K-block remap, A/B consistent [R6]
            bf16x8 af[5], bfr[5];
#pragma unroll
            for (int i = 0; i < 5; ++i) {
                const int ca = band * 160 + wrow * 80 + i * 16 + l15;
                af[i] = *reinterpret_cast<const bf16x8*>(
                    &x[ca * 64 + ((n8r ^ sig(ca)) & 7) * 8]);
                const int cb = wcol * 80 + i * 16 + l15;
                bfr[i] = *reinterpret_cast<const bf16x8*>(
                    &x[cb * 64 + ((n8r ^ sig(cb)) & 7) * 8]);
            }
#pragma unroll
            for (int i = 0; i < 5; ++i)
#pragma unroll
                for (int j = 0; j < 5; ++j)
                    acc[i][j] = __builtin_amdgcn_mfma_f32_16x16x32_bf16(
                        af[i], bfr[j], acc[i][j], 0, 0, 0);
        }
        __syncthreads();             // frag reads done + next tile's DMA drained
        cur ^= 1;
    }
#undef STAGE4

    // bf16 partial [160][320], slice (b*2+band)*NCG+cg   [R6-verified mapping]
    unsigned short* Gp = Gpart + (size_t)((b * 2 + band) * NCG + cg) * QSZ;
#pragma unroll
    for (int i = 0; i < 5; ++i) {
        const int gi_base = wrow * 80 + i * 16 + l4 * 4;
#pragma unroll
        for (int j = 0; j < 5; ++j) {
            const int gj = wcol * 80 + j * 16 + l15;
#pragma unroll
            for (int rg = 0; rg < 4; ++rg)
                Gp[(size_t)(gi_base + rg) * DT + gj] = f2bfu(acc[i][j][rg]);
        }
    }
}

// ---------------- kernel 5: reduce NCG bf16 partials -> weighted square sum -------
// grid (25, 16): y = b*2+band, x = slice of 2048 elems (8/thread)   [R5/R6-verified]
__global__ void loss_priv_kernel(const unsigned short* __restrict__ Gpart,
                                 float* __restrict__ out) {
    const int by = blockIdx.y;
    const int band = by & 1;
    const int t = threadIdx.x;
    const int e0 = (blockIdx.x * 256 + t) * 8;
    float g[8];
#pragma unroll
    for (int k = 0; k < 8; ++k) g[k] = 0.f;
    const unsigned short* base = Gpart + (size_t)by * NCG * QSZ + e0;
#pragma unroll 4
    for (int cg = 0; cg < NCG; ++cg) {
        u16x8 p = *reinterpret_cast<const u16x8*>(base + (size_t)cg * QSZ);
#pragma unroll
        for (int k = 0; k < 8; ++k) g[k] += bf2f(p[k]);
    }
    const int ii = e0 / DT;
    const int jj = e0 - ii * DT;
    const int ig = band * 160 + ii;
    const float wgt = ((ig < D1) == (jj < D1)) ? 1.f : -1.f;
    float sum = 0.f;
#pragma unroll
    for (int k = 0; k < 8; ++k) sum += g[k] * g[k];
    sum *= wgt;
#pragma unroll
    for (int off = 1; off < 64; off <<= 1) sum += __shfl_xor(sum, off);
    __shared__ float red[4];
    if ((t & 63) == 0) red[t >> 6] = sum;
    __syncthreads();
    if (t == 0) atomicAdd(out, (red[0] + red[1] + red[2] + red[3]) * 0.125f);
}

// ================= fallback (small ws): R6-proven fused path =================
__device__ __forceinline__ void issue_loads(const float* __restrict__ Vb,
                                            const float* __restrict__ Yb,
                                            const float* __restrict__ rb,
                                            int n0w, int lane,
                                            float4* vf, float4* yf, float* rr) {
#pragma unroll
    for (int j = 0; j < 8; ++j)
        vf[j] = *reinterpret_cast<const float4*>(Vb + (size_t)(n0w + j) * D1 + 4 * lane);
    const int j2 = lane >> 4, k15 = lane & 15;
    yf[0] = *reinterpret_cast<const float4*>(Yb + (size_t)(n0w + 2 * j2) * D2 + 4 * k15);
    yf[1] = *reinterpret_cast<const float4*>(Yb + (size_t)(n0w + 2 * j2 + 1) * D2 + 4 * k15);
#pragma unroll
    for (int j = 0; j < 8; ++j) rr[j] = rb[n0w + j];
}

__device__ __forceinline__ void write_tile(unsigned short* __restrict__ x,
                                           int lane, int w,
                                           const float4* vf, const float4* yf,
                                           const float* rr) {
    const float* vfp = reinterpret_cast<const float*>(vf);
    const float* yfp = reinterpret_cast<const float*>(yf);
#pragma unroll
    for (int cidx = 0; cidx < 4; ++cidx) {
        const int c = 4 * lane + cidx;
        const int u = (w ^ sig(c)) & 7;
        u32x4 p;
        p[0] = packbf2(vfp[0 * 4 + cidx] * rr[0], vfp[1 * 4 + cidx] * rr[1]);
        p[1] = packbf2(vfp[2 * 4 + cidx] * rr[2], vfp[3 * 4 + cidx] * rr[3]);
        p[2] = packbf2(vfp[4 * 4 + cidx] * rr[4], vfp[5 * 4 + cidx] * rr[5]);
        p[3] = packbf2(vfp[6 * 4 + cidx] * rr[6], vfp[7 * 4 + cidx] * rr[7]);
        *reinterpret_cast<u32x4*>(&x[c * 64 + u * 8]) = p;
    }
    const int j2 = lane >> 4, k15 = lane & 15;
    const float r0 = rr[2 * j2], r1 = rr[2 * j2 + 1];
#pragma unroll
    for (int cidx = 0; cidx < 4; ++cidx) {
        const int c = D1 + 4 * k15 + cidx;
        const int u = (w ^ sig(c)) & 7;
        unsigned int p = packbf2(yfp[cidx] * r0, yfp[4 + cidx] * r1);
        *reinterpret_cast<unsigned int*>(&x[c * 64 + u * 8 + j2 * 2]) = p;
    }
}

__global__ void __launch_bounds__(512, 2)
gram_fb_kernel(const float* __restrict__ V, const float* __restrict__ Y,
               const float* __restrict__ rsd, unsigned short* __restrict__ Gpart) {
    const int cg = blockIdx.x;
    const int band = blockIdx.y;
    const int b = blockIdx.z;
    const int t = threadIdx.x;
    const int lane = t & 63;
    const int w = t >> 6;
    const int wrow = w >> 2;
    const int wcol = w & 3;
    const int l15 = lane & 15;
    const int l4 = lane >> 4;

    const float* Vb = V + (size_t)b * NN * D1;
    const float* Yb = Y + (size_t)b * NN * D2;
    const float* rb = rsd + (size_t)b * NN;

    __shared__ __attribute__((aligned(16))) unsigned short xt[DT * 64];

    f32x4 acc[5][5];
#pragma unroll
    for (int i = 0; i < 5; ++i)
#pragma unroll
        for (int j = 0; j < 5; ++j)
            acc[i][j] = (f32x4){0.f, 0.f, 0.f, 0.f};

    float4 vf[8];
    float4 yf[2];
    float rr[8];

    const int n0base = cg * KCH;
    issue_loads(Vb, Yb, rb, n0base + 8 * w, lane, vf, yf, rr);
    write_tile(xt, lane, w, vf, yf, rr);

    for (int tt = 0; tt < KCH / 64; ++tt) {
        __syncthreads();
        if (tt < KCH / 64 - 1)
            issue_loads(Vb, Yb, rb, n0base + (tt + 1) * 64 + 8 * w, lane, vf, yf, rr);
#pragma unroll
        for (int ks = 0; ks < 2; ++ks) {
            const int n8r = 2 * l4 + ks;
            bf16x8 af[5], bfr[5];
#pragma unroll
            for (int i = 0; i < 5; ++i) {
                const int ca = band * 160 + wrow * 80 + i * 16 + l15;
                af[i] = *reinterpret_cast<const bf16x8*>(
                    &xt[ca * 64 + ((n8r ^ sig(ca)) & 7) * 8]);
                const int cb = wcol * 80 + i * 16 + l15;
                bfr[i] = *reinterpret_cast<const bf16x8*>(
                    &xt[cb * 64 + ((n8r ^ sig(cb)) & 7) * 8]);
            }
#pragma unroll
            for (int i = 0; i < 5; ++i)
#pragma unroll
                for (int j = 0; j < 5; ++j)
                    acc[i][j] = __builtin_amdgcn_mfma_f32_16x16x32_bf16(
                        af[i], bfr[j], acc[i][j], 0, 0, 0);
        }
        __syncthreads();
        if (tt < KCH / 64 - 1)
            write_tile(xt, lane, w, vf, yf, rr);
    }

    unsigned short* Gp = Gpart + (size_t)((b * 2 + band) * NCG + cg) * QSZ;
#pragma unroll
    for (int i = 0; i < 5; ++i) {
        const int gi_base = wrow * 80 + i * 16 + l4 * 4;
#pragma unroll
        for (int j = 0; j < 5; ++j) {
            const int gj = wcol * 80 + j * 16 + l15;
#pragma unroll
            for (int rg = 0; rg < 4; ++rg)
                Gp[(size_t)(gi_base + rg) * DT + gj] = f2bfu(acc[i][j][rg]);
        }
    }
}

extern "C" void kernel_launch(void* const* d_in, const int* in_sizes, int n_in,
                              void* d_out, int out_size, void* d_ws, size_t ws_size,
                              hipStream_t stream) {
    const float* V = (const float*)d_in[0];
    const float* Y = (const float*)d_in[1];
    float* out = (float*)d_out;

    char* ws = (char*)d_ws;
    float* s   = (float*)ws;                          // 2048 B
    float* rsd = (float*)(ws + 2048);                 // 524288 B

    const size_t XS_OFF = 2048 + 524288;              // 526336
    const size_t XS_BYTES = (size_t)BB * 256 * DT * 64 * 2;   // 83,886,080
    const size_t GP_BYTES = (size_t)BB * 2 * NCG * QSZ * 2;   // 26,214,400
    const size_t need2 = XS_OFF + XS_BYTES + GP_BYTES;        // ~110.6 MB
    const size_t need1 = XS_OFF + GP_BYTES;

    hipMemsetAsync(s, 0, 2048, stream);
    hipMemsetAsync(d_out, 0, sizeof(float), stream);

    colsum_kernel<<<dim3(32, BB), 256, 0, stream>>>(Y, s);
    rsd_kernel<<<2048, 256, 0, stream>>>(Y, s, rsd);

    if (ws_size >= need2) {
        unsigned short* Xs    = (unsigned short*)(ws + XS_OFF);
        unsigned short* Gpart = (unsigned short*)(ws + XS_OFF + XS_BYTES);
        xt2_kernel<<<dim3(256, 5, BB), 256, 0, stream>>>(V, Y, rsd, Xs);
        gram4_kernel<<<dim3(NCG, 2, BB), 512, 0, stream>>>(Xs, Gpart);
        loss_priv_kernel<<<dim3(25, 16), 256, 0, stream>>>(Gpart, out);
    } else if (ws_size >= need1) {
        unsigned short* Gpart = (unsigned short*)(ws + XS_OFF);
        gram_fb_kernel<<<dim3(NCG, 2, BB), 512, 0, stream>>>(V, Y, rsd, Gpart);
        loss_priv_kernel<<<dim3(25, 16), 256, 0, stream>>>(Gpart, out);
    }
}

// Round 11
// 129.831 us; speedup vs baseline: 1.6318x; 1.6318x over previous
//
#include <hip/hip_runtime.h>
#include <hip/hip_bf16.h>

#define BB 8
#define NN 16384
#define D1 256
#define D2 64
#define DT 320
#define EPSF 1e-12f
#define NCG 32          // K chunks
#define KCH 512         // rows per chunk
#define Q2SZ (160*160)  // quarter slice elems

typedef __attribute__((ext_vector_type(8))) short bf16x8;
typedef __attribute__((ext_vector_type(8))) unsigned short u16x8;
typedef __attribute__((ext_vector_type(4))) unsigned short u16x4;
typedef __attribute__((ext_vector_type(4))) float f32x4;
typedef __attribute__((ext_vector_type(4))) unsigned int u32x4;

__device__ __forceinline__ unsigned int packbf2(float a, float b) {
    unsigned short lo = __builtin_bit_cast(unsigned short, __float2bfloat16(a));
    unsigned short hi = __builtin_bit_cast(unsigned short, __float2bfloat16(b));
    return (unsigned int)lo | ((unsigned int)hi << 16);
}
__device__ __forceinline__ unsigned short f2bfu(float f) {
    return __builtin_bit_cast(unsigned short, __float2bfloat16(f));
}
__device__ __forceinline__ float bf2f(unsigned short u) {
    unsigned int x = (unsigned int)u << 16;
    return __builtin_bit_cast(float, x);
}

// 8-unit swizzle over [c][64-row] bf16 tile (128B rows): element (c, n8*8+k)
// -> unit u = (n8 ^ sig(c)) & 7. Proven conflict-clean for b128 staging writes
// (c = 4*lane+cidx) and <=2-way for b128 frag reads (c = 16m+l15).  [R3/R6/R9]
__device__ __forceinline__ int sig(int c) { return (c ^ (c >> 2)) & 7; }

// ---------------- kernel 1: s[b,c] = sum_n Y[b,n,c] ----------------
__global__ void colsum_kernel(const float* __restrict__ Y, float* __restrict__ s) {
    const int b = blockIdx.y;
    const int chunk = blockIdx.x;
    const int t = threadIdx.x;
    const int c = t & 63;
    const int r = t >> 6;
    const float* Yb = Y + (size_t)b * NN * D2;
    float acc = 0.f;
    const int nbase = chunk * 512;
    for (int k = 0; k < 128; ++k) {
        int n = nbase + k * 4 + r;
        acc += Yb[(size_t)n * D2 + c];
    }
    __shared__ float red[256];
    red[t] = acc;
    __syncthreads();
    if (r == 0) {
        float v = red[c] + red[64 + c] + red[128 + c] + red[192 + c];
        atomicAdd(&s[b * D2 + c], v);
    }
}

// ---------------- kernel 2: rsd[b,n] = (Y[b,n,:].s[b,:] + eps)^(-1/4) ----------------
__global__ void rsd_kernel(const float* __restrict__ Y, const float* __restrict__ s,
                           float* __restrict__ rsd) {
    const int blk = blockIdx.x;
    const int b = blk >> 8;
    const int nb = (blk & 255) * 64;
    const int t = threadIdx.x;
    const int q = t & 3;
    const int nl = t >> 2;
    __shared__ float ss[D2];
    if (t < D2) ss[t] = s[b * D2 + t];
    __syncthreads();
    const int n = nb + nl;
    const float* yrow = Y + (size_t)b * NN * D2 + (size_t)n * D2 + q * 16;
    float dot = 0.f;
#pragma unroll
    for (int i = 0; i < 4; ++i) {
        float4 f = *reinterpret_cast<const float4*>(yrow + i * 4);
        const float* sp = ss + q * 16 + i * 4;
        dot += f.x * sp[0] + f.y * sp[1] + f.z * sp[2] + f.w * sp[3];
    }
    dot += __shfl_xor(dot, 1);
    dot += __shfl_xor(dot, 2);
    if (q == 0) {
        rsd[(size_t)b * NN + n] = rsqrtf(sqrtf(dot + EPSF));
    }
}

// ---------------- staging helper (R6/R9-verified layout, n8 = 2w+p) ----------------
__device__ __forceinline__ void stage_pass(unsigned short* __restrict__ x,
                                           const float* __restrict__ Vb,
                                           const float* __restrict__ Yb,
                                           const float* __restrict__ rb,
                                           int n0, int lane, int n8) {
    const int r0 = n0 + n8 * 8;
    float4 vf[8];
    float rr[8];
#pragma unroll
    for (int j = 0; j < 8; ++j)
        vf[j] = *reinterpret_cast<const float4*>(Vb + (size_t)(r0 + j) * D1 + 4 * lane);
#pragma unroll
    for (int j = 0; j < 8; ++j) rr[j] = rb[r0 + j];
    const float* vfp = reinterpret_cast<const float*>(vf);
#pragma unroll
    for (int cidx = 0; cidx < 4; ++cidx) {
        const int c = 4 * lane + cidx;
        const int u = (n8 ^ sig(c)) & 7;
        u32x4 p;
        p[0] = packbf2(vfp[0 * 4 + cidx] * rr[0], vfp[1 * 4 + cidx] * rr[1]);
        p[1] = packbf2(vfp[2 * 4 + cidx] * rr[2], vfp[3 * 4 + cidx] * rr[3]);
        p[2] = packbf2(vfp[4 * 4 + cidx] * rr[4], vfp[5 * 4 + cidx] * rr[5]);
        p[3] = packbf2(vfp[6 * 4 + cidx] * rr[6], vfp[7 * 4 + cidx] * rr[7]);
        *reinterpret_cast<u32x4*>(&x[c * 64 + u * 8]) = p;
    }
    const int j2 = lane >> 4, k15 = lane & 15;
    float4 yf0 = *reinterpret_cast<const float4*>(Yb + (size_t)(r0 + 2 * j2) * D2 + 4 * k15);
    float4 yf1 = *reinterpret_cast<const float4*>(Yb + (size_t)(r0 + 2 * j2 + 1) * D2 + 4 * k15);
    const float ry0 = rr[2 * j2], ry1 = rr[2 * j2 + 1];
    const float* y0 = &yf0.x;
    const float* y1 = &yf1.x;
#pragma unroll
    for (int cidx = 0; cidx < 4; ++cidx) {
        const int c = D1 + 4 * k15 + cidx;
        const int u = (n8 ^ sig(c)) & 7;
        unsigned int p = packbf2(y0[cidx] * ry0, y1[cidx] * ry1);
        *reinterpret_cast<unsigned int*>(&x[c * 64 + u * 8 + j2 * 2]) = p;
    }
}

// ---------------- kernel 3: fused quarter Gram ----------------
// grid (3 qq, 32 cg, 8 b) = 768 blocks; 256 thr (4 waves 2x2 of 80x80).
// __launch_bounds__(256,2): cap 256 regs -> acc(100 AGPR)+arch fits, NO SPILL,
// 2 blocks/CU resident, phase-staggered.  qq: 0->(0,0) 1->(0,1) 2->(1,1).
__global__ void __launch_bounds__(256, 2)
gram3_kernel(const float* __restrict__ V, const float* __restrict__ Y,
             const float* __restrict__ rsd, unsigned short* __restrict__ Gp2,
             float* __restrict__ Gfull, int priv) {
    const int qq = blockIdx.x;
    const int cg = blockIdx.y;
    const int b = blockIdx.z;
    const int qi = (qq == 2) ? 1 : 0;
    const int qj = (qq == 0) ? 0 : 1;
    const int t = threadIdx.x;
    const int lane = t & 63;
    const int w = t >> 6;          // 0..3
    const int wrow = w >> 1, wcol = w & 1;
    const int l15 = lane & 15, l4 = lane >> 4;

    const float* Vb = V + (size_t)b * NN * D1;
    const float* Yb = Y + (size_t)b * NN * D2;
    const float* rb = rsd + (size_t)b * NN;

    __shared__ __attribute__((aligned(16))) unsigned short xb[DT * 64];  // 40 KB

    f32x4 acc[5][5];
#pragma unroll
    for (int i = 0; i < 5; ++i)
#pragma unroll
        for (int j = 0; j < 5; ++j)
            acc[i][j] = (f32x4){0.f, 0.f, 0.f, 0.f};

    const int n0base = cg * KCH;

    for (int tt = 0; tt < 8; ++tt) {       // 8 tiles of 64 rows
        const int n0 = n0base + tt * 64;
        __syncthreads();                   // previous tile's frag reads done
        stage_pass(xb, Vb, Yb, rb, n0, lane, 2 * w);      // rows 16w..16w+7
        stage_pass(xb, Vb, Yb, rb, n0, lane, 2 * w + 1);  // rows 16w+8..16w+15
        __syncthreads();                   // tile visible

#pragma unroll
        for (int ks = 0; ks < 2; ++ks) {
            const int n8r = 2 * l4 + ks;   // K-block remap, A/B consistent
            bf16x8 bfr[5];
#pragma unroll
            for (int j = 0; j < 5; ++j) {
                const int cb = qj * 160 + wcol * 80 + j * 16 + l15;
                bfr[j] = *reinterpret_cast<const bf16x8*>(
                    &xb[cb * 64 + ((n8r ^ sig(cb)) & 7) * 8]);
            }
#pragma unroll
            for (int i = 0; i < 5; ++i) {
                const int ca = qi * 160 + wrow * 80 + i * 16 + l15;
                bf16x8 af = *reinterpret_cast<const bf16x8*>(
                    &xb[ca * 64 + ((n8r ^ sig(ca)) & 7) * 8]);
#pragma unroll
                for (int j = 0; j < 5; ++j)
                    acc[i][j] = __builtin_amdgcn_mfma_f32_16x16x32_bf16(
                        af, bfr[j], acc[i][j], 0, 0, 0);
            }
        }
    }

    if (priv) {
        // bf16 quarter partial [160][160], slice (b*3+qq)*NCG+cg
        unsigned short* Gp = Gp2 + (size_t)((b * 3 + qq) * NCG + cg) * Q2SZ;
#pragma unroll
        for (int i = 0; i < 5; ++i) {
            const int gi_base = wrow * 80 + i * 16 + l4 * 4;
#pragma unroll
            for (int j = 0; j < 5; ++j) {
                const int gj = wcol * 80 + j * 16 + l15;
#pragma unroll
                for (int rg = 0; rg < 4; ++rg)
                    Gp[(size_t)(gi_base + rg) * 160 + gj] = f2bfu(acc[i][j][rg]);
            }
        }
    } else {
        // atomic fallback into full G; off-diagonal quarter also adds transpose
        float* Gb = Gfull + (size_t)b * DT * DT;
#pragma unroll
        for (int i = 0; i < 5; ++i) {
            const int gi_base = qi * 160 + wrow * 80 + i * 16 + l4 * 4;
#pragma unroll
            for (int j = 0; j < 5; ++j) {
                const int gj = qj * 160 + wcol * 80 + j * 16 + l15;
#pragma unroll
                for (int rg = 0; rg < 4; ++rg) {
                    const int gi = gi_base + rg;
                    atomicAdd(&Gb[(size_t)gi * DT + gj], acc[i][j][rg]);
                    if (qq == 1)
                        atomicAdd(&Gb[(size_t)gj * DT + gi], acc[i][j][rg]);
                }
            }
        }
    }
}

// ---------------- kernel 4: reduce quarters, weighted square sum ----------
// grid (25, 24): y = b*3+qq; x: 1024-elem slices of 160x160 (4/thread)  [R9-verified]
__global__ void loss2_kernel(const unsigned short* __restrict__ Gp2,
                             float* __restrict__ out) {
    const int byq = blockIdx.y;
    const int qq = byq % 3;
    const int qi = (qq == 2) ? 1 : 0;
    const int qj = (qq == 0) ? 0 : 1;
    const int t = threadIdx.x;
    const int e0 = (blockIdx.x * 256 + t) * 4;    // < 25600
    float g0 = 0.f, g1 = 0.f, g2 = 0.f, g3 = 0.f;
    const unsigned short* base = Gp2 + (size_t)byq * NCG * Q2SZ + e0;
#pragma unroll 4
    for (int cg = 0; cg < NCG; ++cg) {
        u16x4 p = *reinterpret_cast<const u16x4*>(base + (size_t)cg * Q2SZ);
        g0 += bf2f(p[0]); g1 += bf2f(p[1]); g2 += bf2f(p[2]); g3 += bf2f(p[3]);
    }
    const int ii = e0 / 160;
    const int jj = e0 - ii * 160;
    const int ig = qi * 160 + ii;
    const int jg = qj * 160 + jj;
    const float wgt = ((ig < D1) == (jg < D1)) ? 1.f : -1.f;
    const float mult = (qq == 1) ? 2.f : 1.f;
    float sum = wgt * mult * (g0 * g0 + g1 * g1 + g2 * g2 + g3 * g3);
#pragma unroll
    for (int off = 1; off < 64; off <<= 1) sum += __shfl_xor(sum, off);
    __shared__ float red[4];
    if ((t & 63) == 0) red[t >> 6] = sum;
    __syncthreads();
    if (t == 0) atomicAdd(out, (red[0] + red[1] + red[2] + red[3]) * 0.125f);
}

// ---------------- kernel 4b: fallback loss over accumulated full G ----------------
__global__ void loss_kernel(const float* __restrict__ G, float* __restrict__ out) {
    const int b = blockIdx.x >> 3;
    const int slice = blockIdx.x & 7;
    const int t = threadIdx.x;
    const float* Gb = G + (size_t)b * DT * DT;
    float sum = 0.f;
    for (int k = 0; k < 50; ++k) {
        const int e = slice * 12800 + k * 256 + t;
        const int i = e / DT;
        const int j = e - i * DT;
        const float gv = Gb[e];
        const float w = ((i < D1) == (j < D1)) ? 1.f : -1.f;
        sum += w * gv * gv;
    }
#pragma unroll
    for (int off = 1; off < 64; off <<= 1) sum += __shfl_xor(sum, off);
    __shared__ float red[4];
    if ((t & 63) == 0) red[t >> 6] = sum;
    __syncthreads();
    if (t == 0) atomicAdd(out, (red[0] + red[1] + red[2] + red[3]) * 0.125f);
}

extern "C" void kernel_launch(void* const* d_in, const int* in_sizes, int n_in,
                              void* d_out, int out_size, void* d_ws, size_t ws_size,
                              hipStream_t stream) {
    const float* V = (const float*)d_in[0];
    const float* Y = (const float*)d_in[1];
    float* out = (float*)d_out;

    char* ws = (char*)d_ws;
    float* s   = (float*)ws;                          // 2048 B
    float* rsd = (float*)(ws + 2048);                 // 524288 B

    const size_t GP_OFF = 2048 + 524288;
    const size_t GP_BYTES = (size_t)BB * 3 * NCG * Q2SZ * 2;   // 39.3 MB
    const int priv = (ws_size >= GP_OFF + GP_BYTES) ? 1 : 0;

    hipMemsetAsync(s, 0, 2048, stream);
    hipMemsetAsync(d_out, 0, sizeof(float), stream);

    colsum_kernel<<<dim3(32, BB), 256, 0, stream>>>(Y, s);
    rsd_kernel<<<2048, 256, 0, stream>>>(Y, s, rsd);

    if (priv) {
        unsigned short* Gp2 = (unsigned short*)(ws + GP_OFF);
        gram3_kernel<<<dim3(3, NCG, BB), 256, 0, stream>>>(V, Y, rsd, Gp2, nullptr, 1);
        loss2_kernel<<<dim3(25, 24), 256, 0, stream>>>(Gp2, out);
    } else {
        float* Gfull = (float*)(ws + GP_OFF);
        hipMemsetAsync(Gfull, 0, (size_t)BB * DT * DT * 4, stream);
        gram3_kernel<<<dim3(3, NCG, BB), 256, 0, stream>>>(V, Y, rsd, nullptr, Gfull, 0);
        loss_kernel<<<64, 256, 0, stream>>>(Gfull, out);
    }
}

// Round 12
// 114.202 us; speedup vs baseline: 1.8551x; 1.1369x over previous
//
#include <hip/hip_runtime.h>
#include <hip/hip_bf16.h>

#define BB 8
#define NN 16384
#define D1 256
#define D2 64
#define DT 320
#define EPSF 1e-12f
#define NCG 32          // K chunks
#define KCH 512         // rows per chunk
#define TILE 32         // rows per phase
#define NPH (KCH/TILE)  // 16 phases
#define Q2SZ (160*160)  // quarter slice elems

typedef __attribute__((ext_vector_type(8))) short bf16x8;
typedef __attribute__((ext_vector_type(4))) unsigned short u16x4;
typedef __attribute__((ext_vector_type(4))) float f32x4;
typedef __attribute__((ext_vector_type(4))) unsigned int u32x4;

__device__ __forceinline__ unsigned int packbf2(float a, float b) {
    unsigned short lo = __builtin_bit_cast(unsigned short, __float2bfloat16(a));
    unsigned short hi = __builtin_bit_cast(unsigned short, __float2bfloat16(b));
    return (unsigned int)lo | ((unsigned int)hi << 16);
}
__device__ __forceinline__ unsigned short f2bfu(float f) {
    return __builtin_bit_cast(unsigned short, __float2bfloat16(f));
}
__device__ __forceinline__ float bf2f(unsigned short u) {
    unsigned int x = (unsigned int)u << 16;
    return __builtin_bit_cast(float, x);
}

// 4-unit swizzle over [c][32-row] bf16 tile: element (c, n8*8+k) at unit
// u = (n8 ^ sig4(c)) & 3.  sig4(4l+cidx) = (cidx^l)&3.  Read-side: 8 lanes per
// 4-bank quad = 2/bank (free). Write-side ~2.5-4-way (R4-tolerated). [R4/R11]
__device__ __forceinline__ int sig4(int c) { return (c ^ (c >> 2)) & 3; }

// ---------------- kernel 1: s[b,c] = sum_n Y[b,n,c] ----------------
__global__ void colsum_kernel(const float* __restrict__ Y, float* __restrict__ s) {
    const int b = blockIdx.y;
    const int chunk = blockIdx.x;
    const int t = threadIdx.x;
    const int c = t & 63;
    const int r = t >> 6;
    const float* Yb = Y + (size_t)b * NN * D2;
    float acc = 0.f;
    const int nbase = chunk * 512;
    for (int k = 0; k < 128; ++k) {
        int n = nbase + k * 4 + r;
        acc += Yb[(size_t)n * D2 + c];
    }
    __shared__ float red[256];
    red[t] = acc;
    __syncthreads();
    if (r == 0) {
        float v = red[c] + red[64 + c] + red[128 + c] + red[192 + c];
        atomicAdd(&s[b * D2 + c], v);
    }
}

// ---------------- kernel 2: rsd[b,n] = (Y[b,n,:].s[b,:] + eps)^(-1/4) ----------------
__global__ void rsd_kernel(const float* __restrict__ Y, const float* __restrict__ s,
                           float* __restrict__ rsd) {
    const int blk = blockIdx.x;
    const int b = blk >> 8;
    const int nb = (blk & 255) * 64;
    const int t = threadIdx.x;
    const int q = t & 3;
    const int nl = t >> 2;
    __shared__ float ss[D2];
    if (t < D2) ss[t] = s[b * D2 + t];
    __syncthreads();
    const int n = nb + nl;
    const float* yrow = Y + (size_t)b * NN * D2 + (size_t)n * D2 + q * 16;
    float dot = 0.f;
#pragma unroll
    for (int i = 0; i < 4; ++i) {
        float4 f = *reinterpret_cast<const float4*>(yrow + i * 4);
        const float* sp = ss + q * 16 + i * 4;
        dot += f.x * sp[0] + f.y * sp[1] + f.z * sp[2] + f.w * sp[3];
    }
    dot += __shfl_xor(dot, 1);
    dot += __shfl_xor(dot, 2);
    if (q == 0) {
        rsd[(size_t)b * NN + n] = rsqrtf(sqrtf(dot + EPSF));
    }
}

// ---------------- staging: wave w stages its 8 rows (r0 = n0+8w, n8 = w) --------
// cw = number of V float4-col-groups this quarter needs; voff = V col offset;
// useY = stage Y cols (local base yb).
template <int CW, int VOFF, int USEY, int YB>
__device__ __forceinline__ void issue_q(const float* __restrict__ Vb,
                                        const float* __restrict__ Yb,
                                        const float* __restrict__ rb,
                                        int r0, int lane,
                                        float4* vf, float4* yf, float* rr) {
    if (lane < CW) {
#pragma unroll
        for (int j = 0; j < 8; ++j)
            vf[j] = *reinterpret_cast<const float4*>(
                Vb + (size_t)(r0 + j) * D1 + VOFF + 4 * lane);
    }
    if (USEY) {
        const int j2 = lane >> 4, k15 = lane & 15;
        yf[0] = *reinterpret_cast<const float4*>(Yb + (size_t)(r0 + 2 * j2) * D2 + 4 * k15);
        yf[1] = *reinterpret_cast<const float4*>(Yb + (size_t)(r0 + 2 * j2 + 1) * D2 + 4 * k15);
    }
#pragma unroll
    for (int j = 0; j < 8; ++j) rr[j] = rb[r0 + j];
}

template <int CW, int USEY, int YB>
__device__ __forceinline__ void write_q(unsigned short* __restrict__ x,
                                        int lane, int w,
                                        const float4* vf, const float4* yf,
                                        const float* rr) {
    const float* vfp = reinterpret_cast<const float*>(vf);
    if (lane < CW) {
#pragma unroll
        for (int cidx = 0; cidx < 4; ++cidx) {
            const int c = 4 * lane + cidx;            // local col
            const int u = (w ^ sig4(c)) & 3;
            u32x4 p;
            p[0] = packbf2(vfp[0 * 4 + cidx] * rr[0], vfp[1 * 4 + cidx] * rr[1]);
            p[1] = packbf2(vfp[2 * 4 + cidx] * rr[2], vfp[3 * 4 + cidx] * rr[3]);
            p[2] = packbf2(vfp[4 * 4 + cidx] * rr[4], vfp[5 * 4 + cidx] * rr[5]);
            p[3] = packbf2(vfp[6 * 4 + cidx] * rr[6], vfp[7 * 4 + cidx] * rr[7]);
            *reinterpret_cast<u32x4*>(&x[c * TILE + u * 8]) = p;
        }
    }
    if (USEY) {
        const int j2 = lane >> 4, k15 = lane & 15;
        const float ry0 = rr[2 * j2], ry1 = rr[2 * j2 + 1];
        const float* y0 = reinterpret_cast<const float*>(&yf[0]);
        const float* y1 = reinterpret_cast<const float*>(&yf[1]);
#pragma unroll
        for (int cidx = 0; cidx < 4; ++cidx) {
            const int c = YB + 4 * k15 + cidx;        // local col
            const int u = (w ^ sig4(c)) & 3;
            unsigned int p = packbf2(y0[cidx] * ry0, y1[cidx] * ry1);
            *reinterpret_cast<unsigned int*>(&x[c * TILE + u * 8 + j2 * 2]) = p;
        }
    }
}

// ---------------- kernel 3: fused triangle-quarter Gram, R4 phase engine ---------
// grid (3 qq, 32 cg, 8 b) = 768 blocks; 256 thr (4 waves 2x2 of 80x80), 2 co-res/CU.
// qq: 0->(0,0) [cols 0..159]  1->(0,1) [all 320]  2->(1,1) [cols 160..319 local].
__global__ void __launch_bounds__(256, 2)
gram5_kernel(const float* __restrict__ V, const float* __restrict__ Y,
             const float* __restrict__ rsd, unsigned short* __restrict__ Gp2,
             float* __restrict__ Gfull, int priv) {
    const int qq = blockIdx.x;
    const int cg = blockIdx.y;
    const int b = blockIdx.z;
    const int qi = (qq == 2) ? 1 : 0;
    const int qj = (qq == 0) ? 0 : 1;
    const int t = threadIdx.x;
    const int lane = t & 63;
    const int w = t >> 6;          // 0..3
    const int wrow = w >> 1, wcol = w & 1;
    const int l15 = lane & 15, l4 = lane >> 4;

    const float* Vb = V + (size_t)b * NN * D1;
    const float* Yb = Y + (size_t)b * NN * D2;
    const float* rb = rsd + (size_t)b * NN;

    // double-buffered local tile: [c][4 units x 8 rows]; q01 uses 320 cols, else 160
    __shared__ __attribute__((aligned(16))) unsigned short xb[2][DT * TILE]; // 40 KB

    f32x4 acc[5][5];
#pragma unroll
    for (int i = 0; i < 5; ++i)
#pragma unroll
        for (int j = 0; j < 5; ++j)
            acc[i][j] = (f32x4){0.f, 0.f, 0.f, 0.f};

    float4 vf[8];
    float4 yf[2];
    float rr[8];

    const int n0base = cg * KCH;
    const int bbase = (qq == 1) ? 160 : 0;   // B-frag local col base

#define ISSUE(r0)                                                          \
    {                                                                      \
        if (qq == 0)      issue_q<40, 0, 0, 0>(Vb, Yb, rb, (r0), lane, vf, yf, rr); \
        else if (qq == 1) issue_q<64, 0, 1, 256>(Vb, Yb, rb, (r0), lane, vf, yf, rr); \
        else              issue_q<24, 160, 1, 96>(Vb, Yb, rb, (r0), lane, vf, yf, rr); \
    }
#define WRITE(buf)                                                         \
    {                                                                      \
        if (qq == 0)      write_q<40, 0, 0>(xb[buf], lane, w, vf, yf, rr); \
        else if (qq == 1) write_q<64, 1, 256>(xb[buf], lane, w, vf, yf, rr); \
        else              write_q<24, 1, 96>(xb[buf], lane, w, vf, yf, rr); \
    }

    // prologue: stage phase 0 into buf 0
    ISSUE(n0base + 8 * w);
    WRITE(0);
    __syncthreads();

    for (int tt = 0; tt < NPH; ++tt) {
        if (tt < NPH - 1)
            ISSUE(n0base + (tt + 1) * TILE + 8 * w);

        const unsigned short* x = xb[tt & 1];
        bf16x8 af[5], bfr[5];
#pragma unroll
        for (int i = 0; i < 5; ++i) {
            const int ca = wrow * 80 + i * 16 + l15;            // local A col
            af[i] = *reinterpret_cast<const bf16x8*>(
                &x[ca * TILE + ((l4 ^ sig4(ca)) & 3) * 8]);
            const int cb = bbase + wcol * 80 + i * 16 + l15;    // local B col
            bfr[i] = *reinterpret_cast<const bf16x8*>(
                &x[cb * TILE + ((l4 ^ sig4(cb)) & 3) * 8]);
        }
#pragma unroll
        for (int i = 0; i < 5; ++i)
#pragma unroll
            for (int j = 0; j < 5; ++j)
                acc[i][j] = __builtin_amdgcn_mfma_f32_16x16x32_bf16(
                    af[i], bfr[j], acc[i][j], 0, 0, 0);

        if (tt < NPH - 1)
            WRITE((tt + 1) & 1);
        __syncthreads();
    }
#undef ISSUE
#undef WRITE

    if (priv) {
        // bf16 quarter partial [160][160], slice (b*3+qq)*NCG+cg  [R9/R11-verified]
        unsigned short* Gp = Gp2 + (size_t)((b * 3 + qq) * NCG + cg) * Q2SZ;
#pragma unroll
        for (int i = 0; i < 5; ++i) {
            const int gi_base = wrow * 80 + i * 16 + l4 * 4;
#pragma unroll
            for (int j = 0; j < 5; ++j) {
                const int gj = wcol * 80 + j * 16 + l15;
#pragma unroll
                for (int rg = 0; rg < 4; ++rg)
                    Gp[(size_t)(gi_base + rg) * 160 + gj] = f2bfu(acc[i][j][rg]);
            }
        }
    } else {
        float* Gb = Gfull + (size_t)b * DT * DT;
#pragma unroll
        for (int i = 0; i < 5; ++i) {
            const int gi_base = qi * 160 + wrow * 80 + i * 16 + l4 * 4;
#pragma unroll
            for (int j = 0; j < 5; ++j) {
                const int gj = qj * 160 + wcol * 80 + j * 16 + l15;
#pragma unroll
                for (int rg = 0; rg < 4; ++rg) {
                    const int gi = gi_base + rg;
                    atomicAdd(&Gb[(size_t)gi * DT + gj], acc[i][j][rg]);
                    if (qq == 1)
                        atomicAdd(&Gb[(size_t)gj * DT + gi], acc[i][j][rg]);
                }
            }
        }
    }
}

// ---------------- kernel 4: reduce quarters, weighted square sum [R11-verified] ----
__global__ void loss2_kernel(const unsigned short* __restrict__ Gp2,
                             float* __restrict__ out) {
    const int byq = blockIdx.y;
    const int qq = byq % 3;
    const int qi = (qq == 2) ? 1 : 0;
    const int qj = (qq == 0) ? 0 : 1;
    const int t = threadIdx.x;
    const int e0 = (blockIdx.x * 256 + t) * 4;    // < 25600
    float g0 = 0.f, g1 = 0.f, g2 = 0.f, g3 = 0.f;
    const unsigned short* base = Gp2 + (size_t)byq * NCG * Q2SZ + e0;
#pragma unroll 4
    for (int cg = 0; cg < NCG; ++cg) {
        u16x4 p = *reinterpret_cast<const u16x4*>(base + (size_t)cg * Q2SZ);
        g0 += bf2f(p[0]); g1 += bf2f(p[1]); g2 += bf2f(p[2]); g3 += bf2f(p[3]);
    }
    const int ii = e0 / 160;
    const int jj = e0 - ii * 160;
    const int ig = qi * 160 + ii;
    const int jg = qj * 160 + jj;
    const float wgt = ((ig < D1) == (jg < D1)) ? 1.f : -1.f;
    const float mult = (qq == 1) ? 2.f : 1.f;
    float sum = wgt * mult * (g0 * g0 + g1 * g1 + g2 * g2 + g3 * g3);
#pragma unroll
    for (int off = 1; off < 64; off <<= 1) sum += __shfl_xor(sum, off);
    __shared__ float red[4];
    if ((t & 63) == 0) red[t >> 6] = sum;
    __syncthreads();
    if (t == 0) atomicAdd(out, (red[0] + red[1] + red[2] + red[3]) * 0.125f);
}

// ---------------- kernel 4b: fallback loss over accumulated full G ----------------
__global__ void loss_kernel(const float* __restrict__ G, float* __restrict__ out) {
    const int b = blockIdx.x >> 3;
    const int slice = blockIdx.x & 7;
    const int t = threadIdx.x;
    const float* Gb = G + (size_t)b * DT * DT;
    float sum = 0.f;
    for (int k = 0; k < 50; ++k) {
        const int e = slice * 12800 + k * 256 + t;
        const int i = e / DT;
        const int j = e - i * DT;
        const float gv = Gb[e];
        const float w = ((i < D1) == (j < D1)) ? 1.f : -1.f;
        sum += w * gv * gv;
    }
#pragma unroll
    for (int off = 1; off < 64; off <<= 1) sum += __shfl_xor(sum, off);
    __shared__ float red[4];
    if ((t & 63) == 0) red[t >> 6] = sum;
    __syncthreads();
    if (t == 0) atomicAdd(out, (red[0] + red[1] + red[2] + red[3]) * 0.125f);
}

extern "C" void kernel_launch(void* const* d_in, const int* in_sizes, int n_in,
                              void* d_out, int out_size, void* d_ws, size_t ws_size,
                              hipStream_t stream) {
    const float* V = (const float*)d_in[0];
    const float* Y = (const float*)d_in[1];
    float* out = (float*)d_out;

    char* ws = (char*)d_ws;
    float* s   = (float*)ws;                          // 2048 B
    float* rsd = (float*)(ws + 2048);                 // 524288 B

    const size_t GP_OFF = 2048 + 524288;
    const size_t GP_BYTES = (size_t)BB * 3 * NCG * Q2SZ * 2;   // 39.3 MB
    const int priv = (ws_size >= GP_OFF + GP_BYTES) ? 1 : 0;

    hipMemsetAsync(s, 0, 2048, stream);
    hipMemsetAsync(d_out, 0, sizeof(float), stream);

    colsum_kernel<<<dim3(32, BB), 256, 0, stream>>>(Y, s);
    rsd_kernel<<<2048, 256, 0, stream>>>(Y, s, rsd);

    if (priv) {
        unsigned short* Gp2 = (unsigned short*)(ws + GP_OFF);
        gram5_kernel<<<dim3(3, NCG, BB), 256, 0, stream>>>(V, Y, rsd, Gp2, nullptr, 1);
        loss2_kernel<<<dim3(25, 24), 256, 0, stream>>>(Gp2, out);
    } else {
        float* Gfull = (float*)(ws + GP_OFF);
        hipMemsetAsync(Gfull, 0, (size_t)BB * DT * DT * 4, stream);
        gram5_kernel<<<dim3(3, NCG, BB), 256, 0, stream>>>(V, Y, rsd, nullptr, Gfull, 0);
        loss_kernel<<<64, 256, 0, stream>>>(Gfull, out);
    }
}